// Round 17
// baseline (64.617 us; speedup 1.0000x reference)
//
#include <hip/hip_runtime.h>
#include <cstdint>

#define DD  128
#define CAP 32     // bucket slots/node
#define SEB 2048   // edges per stage block
#define OVC 1024   // overflow slots per partition (never used for Poisson(12))
#define PSH 7      // partition shift: 128 nodes/partition, 9-bit partition id

typedef __attribute__((ext_vector_type(8))) short bf16x8;
typedef __attribute__((ext_vector_type(8))) unsigned short ushort8_t;
typedef __attribute__((ext_vector_type(4))) float f32x4;
typedef __attribute__((ext_vector_type(2))) float f32x2;

__device__ __forceinline__ short f2bf(float f) {
    union { float f; unsigned u; } v; v.f = f;
    unsigned r = v.u + 0x7FFFu + ((v.u >> 16) & 1u);   // RNE
    return (short)(r >> 16);
}
__device__ __forceinline__ float bf2f(unsigned short s) {
    union { unsigned u; float f; } v; v.u = ((unsigned)s) << 16;
    return v.f;
}
__device__ __forceinline__ int load_idx(const void* ei, int flag, long long pos) {
    if (flag) return ((const int*)ei)[pos];
    return (int)((const long long*)ei)[pos];
}

// ---------------------------------------------------------------------------
// Kernel 1: stage (counting-sort per block by 9-bit partition = dst>>7) + GEMM.
// (unchanged from R16 — see comments there)
// ---------------------------------------------------------------------------
__global__ __launch_bounds__(256) void stage_gemm(const void* ei, int E, int N,
                                                  int SBLK,
                                                  unsigned* __restrict__ seg,
                                                  int* __restrict__ blkhist,
                                                  int* __restrict__ blkoff,
                                                  const float* __restrict__ W,
                                                  const float* __restrict__ x,
                                                  short* __restrict__ xw,
                                                  unsigned char* __restrict__ xwq) {
    union SMem {
        struct {
            unsigned epack[SEB];
            unsigned sorted[SEB];
            int hist[512];
            int scan[256];
            int curs[512];
            int flag;
        } st;
        short wp[DD * 136];   // 34816 B
    };
    __shared__ SMem sm;
    const int tid = threadIdx.x;
    const int bid = blockIdx.x;

    if (bid < SBLK) {
        if (tid == 0) sm.st.flag = 0;
        sm.st.hist[tid] = 0;
        sm.st.hist[tid + 256] = 0;
        __syncthreads();
        {   // dtype detect: packed-int32 slot reads >=2^32 unless hi==0 (p=2e-5)
            const int n = E < 256 ? E : 256;
            if (tid < n) {
                const long long v = ((const long long*)ei)[tid];
                if (v < 0 || v >= (1LL << 32)) atomicOr(&sm.st.flag, 1);
            }
        }
        __syncthreads();
        const int f = sm.st.flag;
        const int base_e = bid * SEB;
        const int ne = min(SEB, E - base_e);

        for (int i = tid; i < ne; i += 256) {
            const unsigned s = (unsigned)load_idx(ei, f, base_e + i);
            const unsigned t = (unsigned)load_idx(ei, f, (long long)E + base_e + i);
            sm.st.epack[i] = (t << 16) | s;
        }
        __syncthreads();
        for (int i = tid; i < ne; i += 256)
            atomicAdd(&sm.st.hist[sm.st.epack[i] >> 23], 1);   // part = dst>>7
        __syncthreads();
        const int h0 = sm.st.hist[2 * tid];
        const int h1 = sm.st.hist[2 * tid + 1];
        blkhist[bid * 512 + 2 * tid]     = h0;
        blkhist[bid * 512 + 2 * tid + 1] = h1;
        sm.st.scan[tid] = h0 + h1;
        __syncthreads();
        for (int off = 1; off < 256; off <<= 1) {
            const int v = (tid >= off) ? sm.st.scan[tid - off] : 0;
            __syncthreads();
            sm.st.scan[tid] += v;
            __syncthreads();
        }
        const int boff0 = sm.st.scan[tid] - (h0 + h1);
        const int boff1 = boff0 + h0;
        blkoff[bid * 512 + 2 * tid]     = boff0;
        blkoff[bid * 512 + 2 * tid + 1] = boff1;
        sm.st.curs[2 * tid]     = boff0;
        sm.st.curs[2 * tid + 1] = boff1;
        __syncthreads();
        for (int i = tid; i < ne; i += 256) {
            const unsigned u = sm.st.epack[i];
            const int pos = atomicAdd(&sm.st.curs[u >> 23], 1); // LDS atomic
            sm.st.sorted[pos] = u & 0x007FFFFFu;                 // dstl7|src16
        }
        __syncthreads();
        for (int i = tid; i < ne; i += 256)                      // coalesced
            seg[(size_t)bid * SEB + i] = sm.st.sorted[i];
        return;
    }

    // ---- GEMM phase: pack W once, two 64-row sub-tiles ----
    for (int e = tid; e < DD * DD; e += 256) {
        const int k = e >> 7, n = e & 127;
        sm.wp[n * 136 + k] = f2bf(W[e]);
    }
    __syncthreads();

    const int tile = bid - SBLK;
    const int wave = tid >> 6;
    const int lane = tid & 63;
    const int lmod = lane & 15;
    const int lgrp = lane >> 4;

    for (int half = 0; half < 2; ++half) {
        const int rowbase = tile * 128 + half * 64 + wave * 16;
        const int arow = rowbase + lmod;
        const bool aok = arow < N;
        if (rowbase >= N) break;

        f32x4 acc[8];
#pragma unroll
        for (int i = 0; i < 8; ++i) acc[i] = (f32x4){0.f, 0.f, 0.f, 0.f};

#pragma unroll
        for (int ks = 0; ks < 4; ++ks) {
            const int kbase = ks * 32 + lgrp * 8;
            bf16x8 afrag;
            if (aok) {
                const float4 a0 = *(const float4*)&x[(size_t)arow * DD + kbase];
                const float4 a1 = *(const float4*)&x[(size_t)arow * DD + kbase + 4];
                afrag[0] = f2bf(a0.x); afrag[1] = f2bf(a0.y);
                afrag[2] = f2bf(a0.z); afrag[3] = f2bf(a0.w);
                afrag[4] = f2bf(a1.x); afrag[5] = f2bf(a1.y);
                afrag[6] = f2bf(a1.z); afrag[7] = f2bf(a1.w);
            } else {
#pragma unroll
                for (int i = 0; i < 8; ++i) afrag[i] = 0;
            }
#pragma unroll
            for (int nt = 0; nt < 8; ++nt) {
                const bf16x8 bfrag = *(const bf16x8*)&sm.wp[(nt * 16 + lmod) * 136 + kbase];
                acc[nt] = __builtin_amdgcn_mfma_f32_16x16x32_bf16(afrag, bfrag, acc[nt], 0, 0, 0);
            }
        }

#pragma unroll
        for (int r = 0; r < 4; ++r) {
            const int row = rowbase + lgrp * 4 + r;
            if (row < N) {
#pragma unroll
                for (int nt = 0; nt < 8; ++nt) {
                    const float v = acc[nt][r];
                    xw[(size_t)row * DD + nt * 16 + lmod] = f2bf(v);
                    const unsigned q = __builtin_amdgcn_cvt_pk_fp8_f32(v, v, 0, false);
                    xwq[(size_t)row * DD + nt * 16 + lmod] = (unsigned char)(q & 0xFF);
                }
            }
        }
    }
}

// ---------------------------------------------------------------------------
// Kernel 2: bucket build (unchanged from R16).
// ---------------------------------------------------------------------------
__global__ __launch_bounds__(256) void bucket_kernel(const unsigned* __restrict__ seg,
                                                     const int* __restrict__ blkhist,
                                                     const int* __restrict__ blkoff,
                                                     int SBLK, int N,
                                                     unsigned* __restrict__ ovArea,
                                                     int* __restrict__ ovcnt,
                                                     unsigned short* __restrict__ col,
                                                     int* __restrict__ cnt,
                                                     float* __restrict__ dis) {
    const int part = blockIdx.x;
    const int node0 = part << PSH;
    __shared__ int lcnt[128];
    __shared__ int lov;
    if (threadIdx.x < 128) lcnt[threadIdx.x] = 0;
    if (threadIdx.x == 0) lov = 0;
    __syncthreads();

    for (int b = threadIdx.x; b < SBLK; b += 256) {
        const int off = blkoff[b * 512 + part];
        const int h   = blkhist[b * 512 + part];
        const unsigned* s = &seg[(size_t)b * SEB + off];
        for (int k = 0; k < h; ++k) {
            const unsigned u = s[k];
            const int dstl = (u >> 16) & 0x7F;
            const int r = atomicAdd(&lcnt[dstl], 1);
            if (r < CAP) col[(size_t)(node0 + dstl) * CAP + r] = (unsigned short)(u & 0xFFFFu);
            else {
                const int o = atomicAdd(&lov, 1);
                if (o < OVC) ovArea[part * OVC + o] = u;
            }
        }
    }
    __syncthreads();
    const int node = node0 + threadIdx.x;
    if (threadIdx.x < 128 && node < N) {
        const int c = lcnt[threadIdx.x];
        cnt[node] = c;
        dis[node] = rsqrtf((float)(c + 1));
    }
    if (threadIdx.x == 0) ovcnt[part] = lov;
}

// ---------------------------------------------------------------------------
// Kernel 3: pull-gather, 8 lanes/node, 16B (uint4 fp8 = 16 elems) per lane:
//   out[t] = x[t] + b + d*( d*xw_bf16[t] + sum_j dis[sj] * fp8dec(xwq[sj]) )
// 8 nodes/wave (2x MLP vs 16-lane); col = one uint2/lane (4 slots); shfl w=8.
// ---------------------------------------------------------------------------
__global__ __launch_bounds__(256) void gather_kernel(const short* __restrict__ xw,
                                                     const unsigned char* __restrict__ xwq,
                                                     const float* __restrict__ x,
                                                     const float* __restrict__ b,
                                                     const int* __restrict__ cnt,
                                                     const float* __restrict__ dis,
                                                     const unsigned short* __restrict__ col,
                                                     const unsigned* __restrict__ ovArea,
                                                     const int* __restrict__ ovcnt,
                                                     const unsigned* __restrict__ seg,
                                                     const int* __restrict__ blkhist,
                                                     const int* __restrict__ blkoff,
                                                     int SBLK,
                                                     float* __restrict__ out, int N) {
    const int node = blockIdx.x * 32 + (threadIdx.x >> 3);
    if (node >= N) return;
    const int l = threadIdx.x & 7;              // lane within 8-lane node group
    const ushort8_t* xw8 = (const ushort8_t*)xw;
    const uint4* xq4 = (const uint4*)xwq;       // 16 fp8 / load; 8 loads per row

    const int deg = cnt[node];
    const int nbk = deg < CAP ? deg : CAP;
    const float d = dis[node];

    // x/out: 512B row, lane covers 64B = 4 float4 (indices l*4..l*4+3 of 32)
    const float4* xr = (const float4*)&x[(size_t)node * DD];
    const float4 x0 = xr[l * 4 + 0], x1 = xr[l * 4 + 1];
    const float4 x2 = xr[l * 4 + 2], x3 = xr[l * 4 + 3];
    const float4* br = (const float4*)b;
    const float4 b0 = br[l * 4 + 0], b1 = br[l * 4 + 1];
    const float4 b2 = br[l * 4 + 2], b3 = br[l * 4 + 3];

    // col row: 32 u16 = 8 uint2; lane l holds slots 4l..4l+3
    const uint2 ir = ((const uint2*)col)[(size_t)node * 8 + l];
    const int s0 = (4 * l     < nbk) ? (int)(ir.x & 0xFFFFu) : 0;
    const int s1 = (4 * l + 1 < nbk) ? (int)(ir.x >> 16) : 0;
    const int s2 = (4 * l + 2 < nbk) ? (int)(ir.y & 0xFFFFu) : 0;
    const int s3 = (4 * l + 3 < nbk) ? (int)(ir.y >> 16) : 0;
    const float da = dis[s0], db = dis[s1], dc = dis[s2], dd_ = dis[s3];

    // self row (bf16): 16 ushort8 per row; lane covers 2 (elems 16l..16l+15)
    const ushort8_t sv0 = xw8[(size_t)node * 16 + l * 2];
    const ushort8_t sv1 = xw8[(size_t)node * 16 + l * 2 + 1];

    float acc[16], ac2[16];
#pragma unroll
    for (int e = 0; e < 8; ++e) {
        acc[e]     = d * bf2f(sv0[e]);  ac2[e] = 0.f;
        acc[e + 8] = d * bf2f(sv1[e]);  ac2[e + 8] = 0.f;
    }

    int j = 0;
    for (; j + 4 <= nbk; j += 4) {              // 4 x 16B gathers in flight
        int   sj[4];
        float dj[4];
#pragma unroll
        for (int u = 0; u < 4; ++u) {           // j%4==0 -> comp = u (const)
            const int   sel_s = (u == 0) ? s0 : (u == 1) ? s1 : (u == 2) ? s2 : s3;
            const float sel_d = (u == 0) ? da : (u == 1) ? db : (u == 2) ? dc : dd_;
            sj[u] = __shfl(sel_s, (j + u) >> 2, 8);
            dj[u] = __shfl(sel_d, (j + u) >> 2, 8);
        }
        uint4 v[4];
#pragma unroll
        for (int u = 0; u < 4; ++u) v[u] = xq4[(size_t)sj[u] * 8 + l];
#pragma unroll
        for (int u = 0; u < 4; ++u) {
            float* A = (u & 1) ? ac2 : acc;
            const unsigned w0 = v[u].x, w1 = v[u].y, w2 = v[u].z, w3 = v[u].w;
            const f32x2 p0 = __builtin_amdgcn_cvt_pk_f32_fp8(w0, false);
            const f32x2 p1 = __builtin_amdgcn_cvt_pk_f32_fp8(w0, true);
            const f32x2 p2 = __builtin_amdgcn_cvt_pk_f32_fp8(w1, false);
            const f32x2 p3 = __builtin_amdgcn_cvt_pk_f32_fp8(w1, true);
            const f32x2 p4 = __builtin_amdgcn_cvt_pk_f32_fp8(w2, false);
            const f32x2 p5 = __builtin_amdgcn_cvt_pk_f32_fp8(w2, true);
            const f32x2 p6 = __builtin_amdgcn_cvt_pk_f32_fp8(w3, false);
            const f32x2 p7 = __builtin_amdgcn_cvt_pk_f32_fp8(w3, true);
            const float dj_ = dj[u];
            A[0]  = fmaf(dj_, p0[0], A[0]);  A[1]  = fmaf(dj_, p0[1], A[1]);
            A[2]  = fmaf(dj_, p1[0], A[2]);  A[3]  = fmaf(dj_, p1[1], A[3]);
            A[4]  = fmaf(dj_, p2[0], A[4]);  A[5]  = fmaf(dj_, p2[1], A[5]);
            A[6]  = fmaf(dj_, p3[0], A[6]);  A[7]  = fmaf(dj_, p3[1], A[7]);
            A[8]  = fmaf(dj_, p4[0], A[8]);  A[9]  = fmaf(dj_, p4[1], A[9]);
            A[10] = fmaf(dj_, p5[0], A[10]); A[11] = fmaf(dj_, p5[1], A[11]);
            A[12] = fmaf(dj_, p6[0], A[12]); A[13] = fmaf(dj_, p6[1], A[13]);
            A[14] = fmaf(dj_, p7[0], A[14]); A[15] = fmaf(dj_, p7[1], A[15]);
        }
    }
    for (; j < nbk; ++j) {
        const int   comp = j & 3;
        const int   sel_s = (comp == 0) ? s0 : (comp == 1) ? s1 : (comp == 2) ? s2 : s3;
        const float sel_d = (comp == 0) ? da : (comp == 1) ? db : (comp == 2) ? dc : dd_;
        const int   sj = __shfl(sel_s, j >> 2, 8);
        const float dj = __shfl(sel_d, j >> 2, 8);
        const uint4 v = xq4[(size_t)sj * 8 + l];
        const f32x2 p0 = __builtin_amdgcn_cvt_pk_f32_fp8(v.x, false);
        const f32x2 p1 = __builtin_amdgcn_cvt_pk_f32_fp8(v.x, true);
        const f32x2 p2 = __builtin_amdgcn_cvt_pk_f32_fp8(v.y, false);
        const f32x2 p3 = __builtin_amdgcn_cvt_pk_f32_fp8(v.y, true);
        const f32x2 p4 = __builtin_amdgcn_cvt_pk_f32_fp8(v.z, false);
        const f32x2 p5 = __builtin_amdgcn_cvt_pk_f32_fp8(v.z, true);
        const f32x2 p6 = __builtin_amdgcn_cvt_pk_f32_fp8(v.w, false);
        const f32x2 p7 = __builtin_amdgcn_cvt_pk_f32_fp8(v.w, true);
        acc[0]  = fmaf(dj, p0[0], acc[0]);  acc[1]  = fmaf(dj, p0[1], acc[1]);
        acc[2]  = fmaf(dj, p1[0], acc[2]);  acc[3]  = fmaf(dj, p1[1], acc[3]);
        acc[4]  = fmaf(dj, p2[0], acc[4]);  acc[5]  = fmaf(dj, p2[1], acc[5]);
        acc[6]  = fmaf(dj, p3[0], acc[6]);  acc[7]  = fmaf(dj, p3[1], acc[7]);
        acc[8]  = fmaf(dj, p4[0], acc[8]);  acc[9]  = fmaf(dj, p4[1], acc[9]);
        acc[10] = fmaf(dj, p5[0], acc[10]); acc[11] = fmaf(dj, p5[1], acc[11]);
        acc[12] = fmaf(dj, p6[0], acc[12]); acc[13] = fmaf(dj, p6[1], acc[13]);
        acc[14] = fmaf(dj, p7[0], acc[14]); acc[15] = fmaf(dj, p7[1], acc[15]);
    }

    if (deg > CAP) {                            // ~never; exactness guards (bf16)
        const int part = node >> PSH, dl = node & ((1 << PSH) - 1);
        const int oc = ovcnt[part];
        if (oc <= OVC) {
            for (int i = 0; i < oc; ++i) {
                const unsigned u = ovArea[part * OVC + i];
                if ((int)((u >> 16) & 0x7F) == dl) {
                    const int src = (int)(u & 0xFFFFu);
                    const float ds = dis[src];
                    const ushort8_t v0 = xw8[(size_t)src * 16 + l * 2];
                    const ushort8_t v1 = xw8[(size_t)src * 16 + l * 2 + 1];
#pragma unroll
                    for (int e = 0; e < 8; ++e) {
                        acc[e]     = fmaf(ds, bf2f(v0[e]), acc[e]);
                        acc[e + 8] = fmaf(ds, bf2f(v1[e]), acc[e + 8]);
                    }
                }
            }
        } else {
            // absolute fallback: recompute neighbor sum from segments (bf16)
#pragma unroll
            for (int e = 0; e < 8; ++e) {
                acc[e]     = d * bf2f(sv0[e]);  ac2[e] = 0.f;
                acc[e + 8] = d * bf2f(sv1[e]);  ac2[e + 8] = 0.f;
            }
            for (int bb = 0; bb < SBLK; ++bb) {
                const int off = blkoff[bb * 512 + part];
                const int h   = blkhist[bb * 512 + part];
                for (int k = 0; k < h; ++k) {
                    const unsigned u = seg[(size_t)bb * SEB + off + k];
                    if ((int)((u >> 16) & 0x7F) == dl) {
                        const int src = (int)(u & 0xFFFFu);
                        const float ds = dis[src];
                        const ushort8_t v0 = xw8[(size_t)src * 16 + l * 2];
                        const ushort8_t v1 = xw8[(size_t)src * 16 + l * 2 + 1];
#pragma unroll
                        for (int e = 0; e < 8; ++e) {
                            acc[e]     = fmaf(ds, bf2f(v0[e]), acc[e]);
                            acc[e + 8] = fmaf(ds, bf2f(v1[e]), acc[e + 8]);
                        }
                    }
                }
            }
        }
    }

    float4 o0, o1, o2, o3;
    o0.x = x0.x + b0.x + d * (acc[0]  + ac2[0]);
    o0.y = x0.y + b0.y + d * (acc[1]  + ac2[1]);
    o0.z = x0.z + b0.z + d * (acc[2]  + ac2[2]);
    o0.w = x0.w + b0.w + d * (acc[3]  + ac2[3]);
    o1.x = x1.x + b1.x + d * (acc[4]  + ac2[4]);
    o1.y = x1.y + b1.y + d * (acc[5]  + ac2[5]);
    o1.z = x1.z + b1.z + d * (acc[6]  + ac2[6]);
    o1.w = x1.w + b1.w + d * (acc[7]  + ac2[7]);
    o2.x = x2.x + b2.x + d * (acc[8]  + ac2[8]);
    o2.y = x2.y + b2.y + d * (acc[9]  + ac2[9]);
    o2.z = x2.z + b2.z + d * (acc[10] + ac2[10]);
    o2.w = x2.w + b2.w + d * (acc[11] + ac2[11]);
    o3.x = x3.x + b3.x + d * (acc[12] + ac2[12]);
    o3.y = x3.y + b3.y + d * (acc[13] + ac2[13]);
    o3.z = x3.z + b3.z + d * (acc[14] + ac2[14]);
    o3.w = x3.w + b3.w + d * (acc[15] + ac2[15]);
    float4* orow = (float4*)&out[(size_t)node * DD];
    orow[l * 4 + 0] = o0;
    orow[l * 4 + 1] = o1;
    orow[l * 4 + 2] = o2;
    orow[l * 4 + 3] = o3;
}

extern "C" void kernel_launch(void* const* d_in, const int* in_sizes, int n_in,
                              void* d_out, int out_size, void* d_ws, size_t ws_size,
                              hipStream_t stream) {
    const float* x  = (const float*)d_in[0];
    const void*  ei = d_in[1];
    const float* W  = (const float*)d_in[2];
    const float* b  = (const float*)d_in[3];
    float* out = (float*)d_out;

    const int N = in_sizes[0] / DD;     // 50000 (pack scheme requires N <= 65536)
    const int E = in_sizes[1] / 2;

    const int SBLK  = (E + SEB - 1) / SEB;       // 293
    const int npart = (N + (1 << PSH) - 1) >> PSH;   // 391

    // Workspace (~28.5 MB), no zero-init required anywhere.
    char* ws = (char*)d_ws;
    size_t off = 0;
    unsigned* seg = (unsigned*)(ws + off);      off += (size_t)SBLK * SEB * 4;
    int* blkhist  = (int*)(ws + off);           off += (size_t)SBLK * 512 * 4;
    int* blkoff   = (int*)(ws + off);           off += (size_t)SBLK * 512 * 4;
    int* cnt      = (int*)(ws + off);           off += (size_t)N * 4;
    float* dis    = (float*)(ws + off);         off += (size_t)N * 4;
    unsigned short* col = (unsigned short*)(ws + off);  off += (size_t)N * CAP * 2;
    off = (off + 255) & ~(size_t)255;
    int* ovcnt    = (int*)(ws + off);           off += 512 * 4;
    unsigned* ovArea = (unsigned*)(ws + off);   off += (size_t)npart * OVC * 4;
    off = (off + 255) & ~(size_t)255;
    short* xw = (short*)(ws + off);             off += (size_t)N * DD * 2;
    unsigned char* xwq = (unsigned char*)(ws + off);

    const int GB = (N + 127) / 128;              // 391
    stage_gemm<<<SBLK + GB, 256, 0, stream>>>(ei, E, N, SBLK, seg, blkhist, blkoff,
                                              W, x, xw, xwq);
    bucket_kernel<<<npart, 256, 0, stream>>>(seg, blkhist, blkoff, SBLK, N,
                                             ovArea, ovcnt, col, cnt, dis);
    gather_kernel<<<(N + 31) / 32, 256, 0, stream>>>(xw, xwq, x, b, cnt, dis, col,
                                                     ovArea, ovcnt, seg, blkhist,
                                                     blkoff, SBLK, out, N);
}

// Round 18
// 60.371 us; speedup vs baseline: 1.0703x; 1.0703x over previous
//
#include <hip/hip_runtime.h>
#include <cstdint>

#define DD  128
#define CAP 32     // bucket slots/node
#define SEB 2048   // edges per stage block
#define OVC 1024   // overflow slots per partition (never used for Poisson(12))
#define PSH 7      // partition shift: 128 nodes/partition, 9-bit partition id

typedef __attribute__((ext_vector_type(8))) short bf16x8;
typedef __attribute__((ext_vector_type(8))) unsigned short ushort8_t;
typedef __attribute__((ext_vector_type(4))) float f32x4;
typedef __attribute__((ext_vector_type(2))) float f32x2;

__device__ __forceinline__ short f2bf(float f) {
    union { float f; unsigned u; } v; v.f = f;
    unsigned r = v.u + 0x7FFFu + ((v.u >> 16) & 1u);   // RNE
    return (short)(r >> 16);
}
__device__ __forceinline__ float bf2f(unsigned short s) {
    union { unsigned u; float f; } v; v.u = ((unsigned)s) << 16;
    return v.f;
}
__device__ __forceinline__ int load_idx(const void* ei, int flag, long long pos) {
    if (flag) return ((const int*)ei)[pos];
    return (int)((const long long*)ei)[pos];
}

// ---------------------------------------------------------------------------
// Kernel 1: stage (counting-sort per block by 9-bit partition = dst>>7) + GEMM.
//  blocks [0,SBLK):  dtype-detect, pack edges (t<<16|s; N<=65536), LDS
//    512-bin histogram, LDS prefix (2 bins/thread), LDS scatter, coalesced
//    segment write (low 23 bits: dstl7|src16) + blkhist/blkoff rows.
//  blocks [SBLK,..): pack W -> LDS bf16 once, two 64-row MFMA sub-tiles
//    (128 rows/block); epilogue writes xw bf16 + xwq fp8 e4m3.
// ---------------------------------------------------------------------------
__global__ __launch_bounds__(256) void stage_gemm(const void* ei, int E, int N,
                                                  int SBLK,
                                                  unsigned* __restrict__ seg,
                                                  int* __restrict__ blkhist,
                                                  int* __restrict__ blkoff,
                                                  const float* __restrict__ W,
                                                  const float* __restrict__ x,
                                                  short* __restrict__ xw,
                                                  unsigned char* __restrict__ xwq) {
    union SMem {
        struct {
            unsigned epack[SEB];
            unsigned sorted[SEB];
            int hist[512];
            int scan[256];
            int curs[512];
            int flag;
        } st;
        short wp[DD * 136];   // 34816 B
    };
    __shared__ SMem sm;
    const int tid = threadIdx.x;
    const int bid = blockIdx.x;

    if (bid < SBLK) {
        if (tid == 0) sm.st.flag = 0;
        sm.st.hist[tid] = 0;
        sm.st.hist[tid + 256] = 0;
        __syncthreads();
        {   // dtype detect: packed-int32 slot reads >=2^32 unless hi==0 (p=2e-5)
            const int n = E < 256 ? E : 256;
            if (tid < n) {
                const long long v = ((const long long*)ei)[tid];
                if (v < 0 || v >= (1LL << 32)) atomicOr(&sm.st.flag, 1);
            }
        }
        __syncthreads();
        const int f = sm.st.flag;
        const int base_e = bid * SEB;
        const int ne = min(SEB, E - base_e);

        for (int i = tid; i < ne; i += 256) {
            const unsigned s = (unsigned)load_idx(ei, f, base_e + i);
            const unsigned t = (unsigned)load_idx(ei, f, (long long)E + base_e + i);
            sm.st.epack[i] = (t << 16) | s;
        }
        __syncthreads();
        for (int i = tid; i < ne; i += 256)
            atomicAdd(&sm.st.hist[sm.st.epack[i] >> 23], 1);   // part = dst>>7
        __syncthreads();
        const int h0 = sm.st.hist[2 * tid];
        const int h1 = sm.st.hist[2 * tid + 1];
        blkhist[bid * 512 + 2 * tid]     = h0;
        blkhist[bid * 512 + 2 * tid + 1] = h1;
        sm.st.scan[tid] = h0 + h1;
        __syncthreads();
        for (int off = 1; off < 256; off <<= 1) {
            const int v = (tid >= off) ? sm.st.scan[tid - off] : 0;
            __syncthreads();
            sm.st.scan[tid] += v;
            __syncthreads();
        }
        const int boff0 = sm.st.scan[tid] - (h0 + h1);
        const int boff1 = boff0 + h0;
        blkoff[bid * 512 + 2 * tid]     = boff0;
        blkoff[bid * 512 + 2 * tid + 1] = boff1;
        sm.st.curs[2 * tid]     = boff0;
        sm.st.curs[2 * tid + 1] = boff1;
        __syncthreads();
        for (int i = tid; i < ne; i += 256) {
            const unsigned u = sm.st.epack[i];
            const int pos = atomicAdd(&sm.st.curs[u >> 23], 1); // LDS atomic
            sm.st.sorted[pos] = u & 0x007FFFFFu;                 // dstl7|src16
        }
        __syncthreads();
        for (int i = tid; i < ne; i += 256)                      // coalesced
            seg[(size_t)bid * SEB + i] = sm.st.sorted[i];
        return;
    }

    // ---- GEMM phase: pack W once, two 64-row sub-tiles ----
    for (int e = tid; e < DD * DD; e += 256) {
        const int k = e >> 7, n = e & 127;
        sm.wp[n * 136 + k] = f2bf(W[e]);
    }
    __syncthreads();

    const int tile = bid - SBLK;
    const int wave = tid >> 6;
    const int lane = tid & 63;
    const int lmod = lane & 15;
    const int lgrp = lane >> 4;

    for (int half = 0; half < 2; ++half) {
        const int rowbase = tile * 128 + half * 64 + wave * 16;
        const int arow = rowbase + lmod;
        const bool aok = arow < N;
        if (rowbase >= N) break;

        f32x4 acc[8];
#pragma unroll
        for (int i = 0; i < 8; ++i) acc[i] = (f32x4){0.f, 0.f, 0.f, 0.f};

#pragma unroll
        for (int ks = 0; ks < 4; ++ks) {
            const int kbase = ks * 32 + lgrp * 8;
            bf16x8 afrag;
            if (aok) {
                const float4 a0 = *(const float4*)&x[(size_t)arow * DD + kbase];
                const float4 a1 = *(const float4*)&x[(size_t)arow * DD + kbase + 4];
                afrag[0] = f2bf(a0.x); afrag[1] = f2bf(a0.y);
                afrag[2] = f2bf(a0.z); afrag[3] = f2bf(a0.w);
                afrag[4] = f2bf(a1.x); afrag[5] = f2bf(a1.y);
                afrag[6] = f2bf(a1.z); afrag[7] = f2bf(a1.w);
            } else {
#pragma unroll
                for (int i = 0; i < 8; ++i) afrag[i] = 0;
            }
#pragma unroll
            for (int nt = 0; nt < 8; ++nt) {
                const bf16x8 bfrag = *(const bf16x8*)&sm.wp[(nt * 16 + lmod) * 136 + kbase];
                acc[nt] = __builtin_amdgcn_mfma_f32_16x16x32_bf16(afrag, bfrag, acc[nt], 0, 0, 0);
            }
        }

#pragma unroll
        for (int r = 0; r < 4; ++r) {
            const int row = rowbase + lgrp * 4 + r;
            if (row < N) {
#pragma unroll
                for (int nt = 0; nt < 8; ++nt) {
                    const float v = acc[nt][r];
                    xw[(size_t)row * DD + nt * 16 + lmod] = f2bf(v);
                    const unsigned q = __builtin_amdgcn_cvt_pk_fp8_f32(v, v, 0, false);
                    xwq[(size_t)row * DD + nt * 16 + lmod] = (unsigned char)(q & 0xFF);
                }
            }
        }
    }
}

// ---------------------------------------------------------------------------
// Kernel 2: bucket build. One block per 128-node partition (391 blocks, ~1.5
// blocks/CU); LDS ranks -> col (u16); cnt AND dis written wholesale.
// ---------------------------------------------------------------------------
__global__ __launch_bounds__(256) void bucket_kernel(const unsigned* __restrict__ seg,
                                                     const int* __restrict__ blkhist,
                                                     const int* __restrict__ blkoff,
                                                     int SBLK, int N,
                                                     unsigned* __restrict__ ovArea,
                                                     int* __restrict__ ovcnt,
                                                     unsigned short* __restrict__ col,
                                                     int* __restrict__ cnt,
                                                     float* __restrict__ dis) {
    const int part = blockIdx.x;
    const int node0 = part << PSH;
    __shared__ int lcnt[128];
    __shared__ int lov;
    if (threadIdx.x < 128) lcnt[threadIdx.x] = 0;
    if (threadIdx.x == 0) lov = 0;
    __syncthreads();

    for (int b = threadIdx.x; b < SBLK; b += 256) {
        const int off = blkoff[b * 512 + part];
        const int h   = blkhist[b * 512 + part];
        const unsigned* s = &seg[(size_t)b * SEB + off];
        for (int k = 0; k < h; ++k) {
            const unsigned u = s[k];
            const int dstl = (u >> 16) & 0x7F;
            const int r = atomicAdd(&lcnt[dstl], 1);
            if (r < CAP) col[(size_t)(node0 + dstl) * CAP + r] = (unsigned short)(u & 0xFFFFu);
            else {
                const int o = atomicAdd(&lov, 1);
                if (o < OVC) ovArea[part * OVC + o] = u;
            }
        }
    }
    __syncthreads();
    const int node = node0 + threadIdx.x;
    if (threadIdx.x < 128 && node < N) {
        const int c = lcnt[threadIdx.x];
        cnt[node] = c;
        dis[node] = rsqrtf((float)(c + 1));
    }
    if (threadIdx.x == 0) ovcnt[part] = lov;
}

// ---------------------------------------------------------------------------
// Kernel 3: pull-gather, 16 lanes/node (R16 known-good):
//   out[t] = x[t] + b + d*( d*xw_bf16[t] + sum_j dis[sj] * fp8dec(xwq[sj]) )
// d from the precomputed dis[] table (no rsqrt on the critical path).
// ---------------------------------------------------------------------------
__global__ __launch_bounds__(256) void gather_kernel(const short* __restrict__ xw,
                                                     const unsigned char* __restrict__ xwq,
                                                     const float* __restrict__ x,
                                                     const float* __restrict__ b,
                                                     const int* __restrict__ cnt,
                                                     const float* __restrict__ dis,
                                                     const unsigned short* __restrict__ col,
                                                     const unsigned* __restrict__ ovArea,
                                                     const int* __restrict__ ovcnt,
                                                     const unsigned* __restrict__ seg,
                                                     const int* __restrict__ blkhist,
                                                     const int* __restrict__ blkoff,
                                                     int SBLK,
                                                     float* __restrict__ out, int N) {
    const int node = blockIdx.x * 16 + (threadIdx.x >> 4);
    if (node >= N) return;
    const int l = threadIdx.x & 15;
    const ushort8_t* xw8 = (const ushort8_t*)xw;
    const uint2* xq2 = (const uint2*)xwq;

    const int deg = cnt[node];
    const int nbk = deg < CAP ? deg : CAP;
    const float d = dis[node];

    const float4 x0 = *(const float4*)&x[(size_t)node * DD + l * 8];
    const float4 x1 = *(const float4*)&x[(size_t)node * DD + l * 8 + 4];
    const float4 b0 = *(const float4*)&b[l * 8];
    const float4 b1 = *(const float4*)&b[l * 8 + 4];

    const unsigned ir = ((const unsigned*)col)[(size_t)node * 16 + l];
    const int s0 = (2 * l     < nbk) ? (int)(ir & 0xFFFFu) : 0;
    const int s1 = (2 * l + 1 < nbk) ? (int)(ir >> 16) : 0;
    const float dsa = dis[s0];
    const float dsb = dis[s1];

    float acc[8], ac2[8];
    const ushort8_t sv = xw8[(size_t)node * 16 + l];      // self row, bf16
#pragma unroll
    for (int e = 0; e < 8; ++e) { acc[e] = d * bf2f(sv[e]); ac2[e] = 0.f; }

    int j = 0;
    for (; j + 8 <= nbk; j += 8) {
        int   sj[8];
        float dj[8];
#pragma unroll
        for (int u = 0; u < 8; ++u) {
            sj[u] = __shfl((u & 1) ? s1 : s0, (j + u) >> 1, 16);
            dj[u] = __shfl((u & 1) ? dsb : dsa, (j + u) >> 1, 16);
        }
        uint2 v[8];
#pragma unroll
        for (int u = 0; u < 8; ++u) v[u] = xq2[(size_t)sj[u] * 16 + l];
#pragma unroll
        for (int u = 0; u < 8; ++u) {
            float* A = (u & 1) ? ac2 : acc;
            const f32x2 p0 = __builtin_amdgcn_cvt_pk_f32_fp8(v[u].x, false);
            const f32x2 p1 = __builtin_amdgcn_cvt_pk_f32_fp8(v[u].x, true);
            const f32x2 p2 = __builtin_amdgcn_cvt_pk_f32_fp8(v[u].y, false);
            const f32x2 p3 = __builtin_amdgcn_cvt_pk_f32_fp8(v[u].y, true);
            A[0] = fmaf(dj[u], p0[0], A[0]); A[1] = fmaf(dj[u], p0[1], A[1]);
            A[2] = fmaf(dj[u], p1[0], A[2]); A[3] = fmaf(dj[u], p1[1], A[3]);
            A[4] = fmaf(dj[u], p2[0], A[4]); A[5] = fmaf(dj[u], p2[1], A[5]);
            A[6] = fmaf(dj[u], p3[0], A[6]); A[7] = fmaf(dj[u], p3[1], A[7]);
        }
    }
    for (; j + 4 <= nbk; j += 4) {
        int   sj[4];
        float dj[4];
#pragma unroll
        for (int u = 0; u < 4; ++u) {
            sj[u] = __shfl((u & 1) ? s1 : s0, (j + u) >> 1, 16);
            dj[u] = __shfl((u & 1) ? dsb : dsa, (j + u) >> 1, 16);
        }
        uint2 v[4];
#pragma unroll
        for (int u = 0; u < 4; ++u) v[u] = xq2[(size_t)sj[u] * 16 + l];
#pragma unroll
        for (int u = 0; u < 4; ++u) {
            float* A = (u & 1) ? ac2 : acc;
            const f32x2 p0 = __builtin_amdgcn_cvt_pk_f32_fp8(v[u].x, false);
            const f32x2 p1 = __builtin_amdgcn_cvt_pk_f32_fp8(v[u].x, true);
            const f32x2 p2 = __builtin_amdgcn_cvt_pk_f32_fp8(v[u].y, false);
            const f32x2 p3 = __builtin_amdgcn_cvt_pk_f32_fp8(v[u].y, true);
            A[0] = fmaf(dj[u], p0[0], A[0]); A[1] = fmaf(dj[u], p0[1], A[1]);
            A[2] = fmaf(dj[u], p1[0], A[2]); A[3] = fmaf(dj[u], p1[1], A[3]);
            A[4] = fmaf(dj[u], p2[0], A[4]); A[5] = fmaf(dj[u], p2[1], A[5]);
            A[6] = fmaf(dj[u], p3[0], A[6]); A[7] = fmaf(dj[u], p3[1], A[7]);
        }
    }
    for (; j < nbk; ++j) {
        const int   sj = __shfl((j & 1) ? s1 : s0, j >> 1, 16);
        const float dj = __shfl((j & 1) ? dsb : dsa, j >> 1, 16);
        const uint2 v = xq2[(size_t)sj * 16 + l];
        const f32x2 p0 = __builtin_amdgcn_cvt_pk_f32_fp8(v.x, false);
        const f32x2 p1 = __builtin_amdgcn_cvt_pk_f32_fp8(v.x, true);
        const f32x2 p2 = __builtin_amdgcn_cvt_pk_f32_fp8(v.y, false);
        const f32x2 p3 = __builtin_amdgcn_cvt_pk_f32_fp8(v.y, true);
        acc[0] = fmaf(dj, p0[0], acc[0]); acc[1] = fmaf(dj, p0[1], acc[1]);
        acc[2] = fmaf(dj, p1[0], acc[2]); acc[3] = fmaf(dj, p1[1], acc[3]);
        acc[4] = fmaf(dj, p2[0], acc[4]); acc[5] = fmaf(dj, p2[1], acc[5]);
        acc[6] = fmaf(dj, p3[0], acc[6]); acc[7] = fmaf(dj, p3[1], acc[7]);
    }

    if (deg > CAP) {                            // ~never; exactness guards
        const int part = node >> PSH, dl = node & ((1 << PSH) - 1);
        const int oc = ovcnt[part];
        if (oc <= OVC) {
            for (int i = 0; i < oc; ++i) {
                const unsigned u = ovArea[part * OVC + i];
                if ((int)((u >> 16) & 0x7F) == dl) {
                    const int src = (int)(u & 0xFFFFu);
                    const ushort8_t v = xw8[(size_t)src * 16 + l];
#pragma unroll
                    for (int e = 0; e < 8; ++e) acc[e] = fmaf(dis[src], bf2f(v[e]), acc[e]);
                }
            }
        } else {
            // absolute fallback: recompute neighbor sum from segments (bf16)
#pragma unroll
            for (int e = 0; e < 8; ++e) { acc[e] = d * bf2f(sv[e]); ac2[e] = 0.f; }
            for (int bb = 0; bb < SBLK; ++bb) {
                const int off = blkoff[bb * 512 + part];
                const int h   = blkhist[bb * 512 + part];
                for (int k = 0; k < h; ++k) {
                    const unsigned u = seg[(size_t)bb * SEB + off + k];
                    if ((int)((u >> 16) & 0x7F) == dl) {
                        const int src = (int)(u & 0xFFFFu);
                        const ushort8_t v = xw8[(size_t)src * 16 + l];
#pragma unroll
                        for (int e = 0; e < 8; ++e) acc[e] = fmaf(dis[src], bf2f(v[e]), acc[e]);
                    }
                }
            }
        }
    }

    float4 o0, o1;
    o0.x = x0.x + b0.x + d * (acc[0] + ac2[0]);
    o0.y = x0.y + b0.y + d * (acc[1] + ac2[1]);
    o0.z = x0.z + b0.z + d * (acc[2] + ac2[2]);
    o0.w = x0.w + b0.w + d * (acc[3] + ac2[3]);
    o1.x = x1.x + b1.x + d * (acc[4] + ac2[4]);
    o1.y = x1.y + b1.y + d * (acc[5] + ac2[5]);
    o1.z = x1.z + b1.z + d * (acc[6] + ac2[6]);
    o1.w = x1.w + b1.w + d * (acc[7] + ac2[7]);
    *(float4*)&out[(size_t)node * DD + l * 8]     = o0;
    *(float4*)&out[(size_t)node * DD + l * 8 + 4] = o1;
}

extern "C" void kernel_launch(void* const* d_in, const int* in_sizes, int n_in,
                              void* d_out, int out_size, void* d_ws, size_t ws_size,
                              hipStream_t stream) {
    const float* x  = (const float*)d_in[0];
    const void*  ei = d_in[1];
    const float* W  = (const float*)d_in[2];
    const float* b  = (const float*)d_in[3];
    float* out = (float*)d_out;

    const int N = in_sizes[0] / DD;     // 50000 (pack scheme requires N <= 65536)
    const int E = in_sizes[1] / 2;

    const int SBLK  = (E + SEB - 1) / SEB;       // 293
    const int npart = (N + (1 << PSH) - 1) >> PSH;   // 391

    // Workspace (~28.5 MB), no zero-init required anywhere.
    char* ws = (char*)d_ws;
    size_t off = 0;
    unsigned* seg = (unsigned*)(ws + off);      off += (size_t)SBLK * SEB * 4;
    int* blkhist  = (int*)(ws + off);           off += (size_t)SBLK * 512 * 4;
    int* blkoff   = (int*)(ws + off);           off += (size_t)SBLK * 512 * 4;
    int* cnt      = (int*)(ws + off);           off += (size_t)N * 4;
    float* dis    = (float*)(ws + off);         off += (size_t)N * 4;
    unsigned short* col = (unsigned short*)(ws + off);  off += (size_t)N * CAP * 2;
    off = (off + 255) & ~(size_t)255;
    int* ovcnt    = (int*)(ws + off);           off += 512 * 4;
    unsigned* ovArea = (unsigned*)(ws + off);   off += (size_t)npart * OVC * 4;
    off = (off + 255) & ~(size_t)255;
    short* xw = (short*)(ws + off);             off += (size_t)N * DD * 2;
    unsigned char* xwq = (unsigned char*)(ws + off);

    const int GB = (N + 127) / 128;              // 391
    stage_gemm<<<SBLK + GB, 256, 0, stream>>>(ei, E, N, SBLK, seg, blkhist, blkoff,
                                              W, x, xw, xwq);
    bucket_kernel<<<npart, 256, 0, stream>>>(seg, blkhist, blkoff, SBLK, N,
                                             ovArea, ovcnt, col, cnt, dis);
    gather_kernel<<<(N + 15) / 16, 256, 0, stream>>>(xw, xwq, x, b, cnt, dis, col,
                                                     ovArea, ovcnt, seg, blkhist,
                                                     blkoff, SBLK, out, N);
}